// Round 20
// baseline (656.769 us; speedup 1.0000x reference)
//
#include <hip/hip_runtime.h>
#include <stdint.h>
#include <stddef.h>

#define NTOK 8192
#define DDIM 1024
#define HDIM 2048
#define NEXP 8
#define GROWS 16384   // total grouped rows = 2*NTOK (top-2)

typedef __attribute__((ext_vector_type(8))) short short8;
typedef __attribute__((ext_vector_type(8))) unsigned short ushort8;
typedef __attribute__((ext_vector_type(4))) float floatx4;

#define AS1 __attribute__((address_space(1)))
#define AS3 __attribute__((address_space(3)))

// pair-tiles: sum over experts of ceil(ceil(Me/128)/2) <= (136+8)/2 = 72
#define MAXT1 (72 * (HDIM / 128))       // 1152  (pairs x by)
#define MAXT2 (72 * (DDIM / 128) * 2)   // 1152  (pairs x by x ksplit2)

// ws layout (bytes)
constexpr size_t OFF_CNT  = 0;                                         // 8 ints
constexpr size_t OFF_TB1  = 256;                                       // 1+MAXT1 ints (pad 4864)
constexpr size_t OFF_TB2  = OFF_TB1 + 4864;                            // 1+MAXT2 ints (pad 4864)
constexpr size_t OFF_TKI  = OFF_TB2 + 4864;                            // NTOK int2
constexpr size_t OFF_TKW  = OFF_TKI + (size_t)NTOK * 8;                // NTOK float2
constexpr size_t OFF_LIST = OFF_TKW + (size_t)NTOK * 8;                // E*N ints
constexpr size_t OFF_WTS  = OFF_LIST + (size_t)NEXP * NTOK * 4;        // E*N floats
constexpr size_t OFF_XBF  = OFF_WTS + (size_t)NEXP * NTOK * 4;         // N*D bf16 (row-major)
constexpr size_t OFF_AKB  = OFF_XBF + (size_t)NTOK * DDIM * 2;         // [32][GROWS][32] bf16
constexpr size_t OFF_W1KB = OFF_AKB + (size_t)GROWS * DDIM * 2;        // [e][32][HDIM][32]
constexpr size_t OFF_W2KB = OFF_W1KB + (size_t)NEXP * DDIM * HDIM * 2; // [e][64][DDIM][32]
constexpr size_t OFF_HKB  = OFF_W2KB + (size_t)NEXP * DDIM * HDIM * 2; // [64][GROWS][32]

__device__ __forceinline__ unsigned short f2bf(float f) {
  union { float f; unsigned u; } v; v.f = f;
  unsigned r = v.u + 0x7FFFu + ((v.u >> 16) & 1u);   // RNE, finite inputs
  return (unsigned short)(r >> 16);
}

// ---------------- gating (one wave per token) + fused x->bf16 pack; NO atomics ----------------
__global__ __launch_bounds__(256) void gate_kernel(
    const float* __restrict__ x, const float* __restrict__ Wg,
    const float* __restrict__ bg, const float* __restrict__ noise,
    int2* __restrict__ tki, float2* __restrict__ tkw,
    unsigned short* __restrict__ xbf) {
  int lane = threadIdx.x & 63;
  int wid  = threadIdx.x >> 6;
  int token = blockIdx.x * 4 + wid;
  const float* xr = x + (size_t)token * DDIM;
  unsigned short* xo = xbf + (size_t)token * DDIM;
  double acc[NEXP];
#pragma unroll
  for (int e = 0; e < NEXP; ++e) acc[e] = 0.0;
  for (int d = lane; d < DDIM; d += 64) {
    float xv = xr[d];
    xo[d] = f2bf(xv);
    const floatx4* wp = (const floatx4*)(Wg + d * NEXP);
    floatx4 w0 = wp[0], w1 = wp[1];
#pragma unroll
    for (int j = 0; j < 4; ++j) {
      acc[j]     += (double)xv * (double)w0[j];
      acc[4 + j] += (double)xv * (double)w1[j];
    }
  }
#pragma unroll
  for (int e = 0; e < NEXP; ++e)
#pragma unroll
    for (int off = 32; off > 0; off >>= 1) acc[e] += __shfl_xor(acc[e], off);
  if (lane == 0) {
    float nv[NEXP];
#pragma unroll
    for (int e = 0; e < NEXP; ++e) {
      float lg = (float)(acc[e] + (double)bg[e]);
      nv[e] = lg + 0.1f * noise[token * NEXP + e];
    }
    int i1 = 0; float v1 = nv[0];
#pragma unroll
    for (int e = 1; e < NEXP; ++e) if (nv[e] > v1) { v1 = nv[e]; i1 = e; }
    int i2 = -1; float v2 = -3.4e38f;
#pragma unroll
    for (int e = 0; e < NEXP; ++e) if (e != i1 && nv[e] > v2) { v2 = nv[e]; i2 = e; }
    float tt  = expf(v2 - v1);
    tki[token] = make_int2(i1, i2);
    tkw[token] = make_float2(1.0f / (1.0f + tt), tt / (1.0f + tt));
  }
}

// ---------------- scatter: one block per expert, ballot-compaction, deterministic ----------------
__global__ __launch_bounds__(256) void scatter_kernel(
    const int2* __restrict__ tki, const float2* __restrict__ tkw,
    int* __restrict__ counts, int* __restrict__ lists, float* __restrict__ wts) {
  int e = blockIdx.x;
  int tid = threadIdx.x;
  int lane = tid & 63, wid = tid >> 6;
  __shared__ int wave_cnt[4];
  __shared__ int run_total;
  if (tid == 0) run_total = 0;
  __syncthreads();
  for (int t0 = 0; t0 < NTOK; t0 += 256) {
    int tok = t0 + tid;
    int2 ki = tki[tok];
    float2 kw = tkw[tok];
    bool sel = (ki.x == e) || (ki.y == e);
    float w = (ki.x == e) ? kw.x : kw.y;
    unsigned long long mask = __ballot(sel);
    int pos = __popcll(mask & ((1ull << lane) - 1ull));
    if (lane == 0) wave_cnt[wid] = __popcll(mask);
    __syncthreads();
    int base = run_total;
    for (int i = 0; i < wid; ++i) base += wave_cnt[i];
    if (sel) {
      lists[e * NTOK + base + pos] = tok;
      wts[e * NTOK + base + pos] = w;
    }
    __syncthreads();
    if (tid == 0) run_total += wave_cnt[0] + wave_cnt[1] + wave_cnt[2] + wave_cnt[3];
    __syncthreads();
  }
  if (tid == 0) counts[e] = run_total;
}

// ---------------- gather A into K-blocked grouped panels: akb[kt32][grow][32] ----------------
__global__ __launch_bounds__(256) void gather_a_kernel(
    const unsigned short* __restrict__ xbf, const int* __restrict__ counts,
    const int* __restrict__ lists, unsigned short* __restrict__ akb) {
  int kt   = blockIdx.y;                       // 0..31
  int grow = blockIdx.x * 256 + threadIdx.x;   // 0..16383
  int c[8];
#pragma unroll
  for (int i = 0; i < 8; ++i) c[i] = counts[i];
  int e = 0, off = 0;
#pragma unroll
  for (int i = 0; i < 8; ++i)
    if (e == i && grow >= off + c[i]) { off += c[i]; e = i + 1; }
  int tok = lists[e * NTOK + (grow - off)];
  const ushort8* s = (const ushort8*)(xbf + (size_t)tok * DDIM + kt * 32);
  ushort8* d = (ushort8*)(akb + (size_t)kt * GROWS * 32 + (size_t)grow * 32);
  d[0] = s[0]; d[1] = s[1]; d[2] = s[2]; d[3] = s[3];
}

// ---------------- tile-table build: PAIRED 128-row tiles ----------------
// tb1: (e, by, p-fastest), desc = e<<16 | p<<8 | by.   p covers bx {2p, 2p+1}.
// tb2: (e, kh, by, p-fastest), desc = kh<<24 | e<<16 | p<<8 | by.
__global__ __launch_bounds__(256) void build_tiles_kernel(
    const int* __restrict__ counts, int* __restrict__ tb1, int* __restrict__ tb2) {
  int tid = threadIdx.x;
  int pr[8], cum[9];
  cum[0] = 0;
#pragma unroll
  for (int e = 0; e < 8; ++e) {
    int ct = (counts[e] + 127) >> 7;
    pr[e] = (ct + 1) >> 1;
    cum[e + 1] = cum[e] + pr[e];
  }
  int np = cum[8];
  constexpr int NBY1 = HDIM / 128, NBY2 = DDIM / 128;
  if (tid == 0) { tb1[0] = np * NBY1; tb2[0] = np * NBY2 * 2; }
  for (int idx = tid; idx < np * NBY1; idx += 256) {
    int e = 0;
    while (idx >= cum[e + 1] * NBY1) ++e;
    int r = idx - cum[e] * NBY1;
    int by = r / pr[e], p = r - by * pr[e];
    tb1[1 + idx] = (e << 16) | (p << 8) | by;
  }
  for (int idx = tid; idx < np * NBY2 * 2; idx += 256) {
    int e = 0;
    while (idx >= cum[e + 1] * NBY2 * 2) ++e;
    int r = idx - cum[e] * NBY2 * 2;
    int khby = r / pr[e], p = r - khby * pr[e];
    int kh = khby / NBY2, by = khby - kh * NBY2;
    tb2[1 + idx] = (kh << 24) | (e << 16) | (p << 8) | by;
  }
}

// ---------------- W [e][R=K][C] f32 -> K-blocked WT_kb [e][K/32][C][32] bf16 ----------------
__global__ __launch_bounds__(256) void transpose_cvt_kernel(
    const float* __restrict__ W, unsigned short* __restrict__ WT, int R, int C) {
  __shared__ float tile[64][65];
  int e = blockIdx.z;
  const float* Win = W + (size_t)e * R * C;
  unsigned short* Wout = WT + (size_t)e * R * C;
  int c0 = blockIdx.x * 64, r0 = blockIdx.y * 64;   // r0 = k-origin
  int tx = threadIdx.x & 63, ty = threadIdx.x >> 6;
#pragma unroll
  for (int i = ty; i < 64; i += 4)
    tile[i][tx] = Win[(size_t)(r0 + i) * C + c0 + tx];
  __syncthreads();
  int cc = threadIdx.x >> 2, seg = (threadIdx.x & 3) * 16;
  ushort8 o0, o1;
#pragma unroll
  for (int j = 0; j < 8; ++j) o0[j] = f2bf(tile[seg + j][cc]);
#pragma unroll
  for (int j = 0; j < 8; ++j) o1[j] = f2bf(tile[seg + 8 + j][cc]);
  int koff = r0 + seg;
  unsigned short* outp = Wout + (size_t)(koff >> 5) * C * 32
                              + (size_t)(c0 + cc) * 32 + (koff & 31);
  *(ushort8*)(outp) = o0;
  *(ushort8*)(outp + 8) = o1;
}

// ---------------- grouped GEMM: DUAL 128x128 tiles/block, BK=32, 4 waves, 2-buf 48KB ------
// R19 post-mortem: schedule space exhausted at 1 tile/block (~153us). New lever: arithmetic
// intensity. One block computes TWO bx row-tiles sharing its staged B-tile: B staged bytes
// halve, MFMA per barrier-pair doubles (32/wave), registers ~196/wave (128 acc AGPR + ~70
// VGPR) -> 2 waves/SIMD -> 2 blocks/CU residency preserved (R13's 1-block register trap
// avoided: 4-wave blocks). Stage = 6 x 4KB-contiguous gl_lds; vmcnt(6)/(0) ladder; swizzle/
// fragments/epilogue = R19 verbatim (x2). G2 keeps K-split x2 for grid size (~1100 blocks).
template <int KDIM, int NDIM, int KSPLIT, bool IS_G1>
__global__ __launch_bounds__(256) void moe_gemm_kernel(
    const unsigned short* __restrict__ Akb,      // [KDIM/32][GROWS][32]
    const unsigned short* __restrict__ Bkb,      // [e][KDIM/32][NDIM][32]
    const float* __restrict__ bias,
    const int* __restrict__ counts, const int* __restrict__ lists,
    const float* __restrict__ wts, const int* __restrict__ tbl,
    unsigned short* __restrict__ Hkb,            // [HDIM/32][GROWS][32]
    float* __restrict__ Out) {
  __shared__ __align__(16) char smem[49152];
  constexpr int KLEN = KDIM / KSPLIT;
  constexpr int NT = KLEN / 32;
  constexpr size_t A_KT = (size_t)GROWS * 32;
  constexpr size_t B_KT = (size_t)NDIM * 32;

  int ntiles = tbl[0];
  int bid = blockIdx.x;
  if (bid >= ntiles) return;
  // bijective XCD-chunk swizzle within [0, ntiles)  (m204)
  int q = ntiles >> 3, rr = ntiles & 7;
  int xcd = bid & 7, within = bid >> 3;
  int widx = (xcd < rr ? xcd * (q + 1) : rr * (q + 1) + (xcd - rr) * q) + within;
  int desc = tbl[1 + widx];
  int kh = (desc >> 24) & 1;
  int e  = (desc >> 16) & 0xff;
  int p  = (desc >> 8) & 0xff;
  int by = desc & 0xff;
  int bx0 = 2 * p, bx1 = 2 * p + 1;

  int Me, off_e = 0;
  {
    int c[8];
#pragma unroll
    for (int i = 0; i < 8; ++i) c[i] = counts[i];
    Me = c[e];
#pragma unroll
    for (int i = 0; i < 8; ++i) if (i < e) off_e += c[i];
  }
  bool has1 = (bx1 * 128 < Me);

  int tid = threadIdx.x;
  int lane = tid & 63, wid = tid >> 6;
  int wr = wid >> 1, wc = wid & 1;       // 2x2 waves, 64x64 output each (per tile)
  int r16 = lane & 15, g4 = lane >> 4;

  // ---- staging sources: row r0=tid>>2 (0..63) per 4KB instr, stored slot tid&3,
  //      source chunk = (tid&3)^((r0>>1)&3); rows consecutive 64B -> 4KB contiguous/instr
  int r0 = tid >> 2;
  int ch = ((tid & 3) ^ ((r0 >> 1) & 3)) * 8;
  int ktbase = kh * NT;
  const unsigned short *sA[2][2], *sB[2];   // [tile][instr], [instr]
#pragma unroll
  for (int tt = 0; tt < 2; ++tt) {
    int bxx = tt ? bx1 : bx0;
#pragma unroll
    for (int i = 0; i < 2; ++i) {
      int lr = bxx * 128 + i * 64 + r0;
      int g = off_e + (lr < Me ? lr : 0);
      sA[tt][i] = Akb + (size_t)ktbase * A_KT + (size_t)g * 32 + ch;
    }
  }
  {
    const unsigned short* be = Bkb + (size_t)e * KDIM * NDIM + (size_t)ktbase * B_KT;
    sB[0] = be + (size_t)(by * 128 + r0) * 32 + ch;
    sB[1] = be + (size_t)(by * 128 + 64 + r0) * 32 + ch;
  }

  auto stage = [&](int t) {              // 6 gl_lds per thread; each instr = 4KB contiguous
    int buf = t & 1;
    char* da0 = smem + buf * 8192 + tid * 16;
    char* da1 = smem + 16384 + buf * 8192 + tid * 16;
    char* db  = smem + 32768 + buf * 8192 + tid * 16;
    size_t ao = (size_t)t * A_KT, bo = (size_t)t * B_KT;
    __builtin_amdgcn_global_load_lds((const AS1 void*)(sA[0][0] + ao), (AS3 void*)da0, 16, 0, 0);
    __builtin_amdgcn_global_load_lds((const AS1 void*)(sA[0][1] + ao), (AS3 void*)(da0 + 4096), 16, 0, 0);
    __builtin_amdgcn_global_load_lds((const AS1 void*)(sA[1][0] + ao), (AS3 void*)da1, 16, 0, 0);
    __builtin_amdgcn_global_load_lds((const AS1 void*)(sA[1][1] + ao), (AS3 void*)(da1 + 4096), 16, 0, 0);
    __builtin_amdgcn_global_load_lds((const AS1 void*)(sB[0] + bo),  (AS3 void*)db, 16, 0, 0);
    __builtin_amdgcn_global_load_lds((const AS1 void*)(sB[1] + bo),  (AS3 void*)(db + 4096), 16, 0, 0);
  };

  // ---- fragment read offsets (swizzled): row*64 + ((g4 ^ ((row>>1)&3))*16)
  int aoff[4], boff[4];
#pragma unroll
  for (int m = 0; m < 4; ++m) {
    int rowa = wr * 64 + m * 16 + r16;
    aoff[m] = rowa * 64 + ((g4 ^ ((rowa >> 1) & 3)) * 16);
  }
#pragma unroll
  for (int n = 0; n < 4; ++n) {
    int rowb = wc * 64 + n * 16 + r16;
    boff[n] = 32768 + rowb * 64 + ((g4 ^ ((rowb >> 1) & 3)) * 16);
  }

  floatx4 acc0[4][4], acc1[4][4];
#pragma unroll
  for (int m = 0; m < 4; ++m)
#pragma unroll
    for (int n = 0; n < 4; ++n) {
      acc0[m][n] = (floatx4){0.f, 0.f, 0.f, 0.f};
      acc1[m][n] = (floatx4){0.f, 0.f, 0.f, 0.f};
    }

  stage(0);
  stage(1);

  for (int t = 0; t < NT; ++t) {
    if (t + 1 < NT) { asm volatile("s_waitcnt vmcnt(6)" ::: "memory"); }  // tile t landed; t+1 flying
    else            { asm volatile("s_waitcnt vmcnt(0)" ::: "memory"); }
    __builtin_amdgcn_s_barrier();
    __builtin_amdgcn_sched_barrier(0);        // no ds_read hoists above barrier (rule #18)
    const char* pa0 = smem + (t & 1) * 8192;
    const char* pa1 = smem + 16384 + (t & 1) * 8192;
    const char* pb  = smem + (t & 1) * 8192;  // boff already includes +32768
    short8 a0[4], a1[4], b[4];
#pragma unroll
    for (int m = 0; m < 4; ++m) {
      a0[m] = *(const short8*)(pa0 + aoff[m]);
      a1[m] = *(const short8*)(pa1 + aoff[m]);
    }
#pragma unroll
    for (int n = 0; n < 4; ++n) b[n] = *(const short8*)(pb + boff[n]);
#pragma unroll
    for (int m = 0; m < 4; ++m)
#pragma unroll
      for (int n = 0; n < 4; ++n) {
        acc0[m][n] = __builtin_amdgcn_mfma_f32_16x16x32_bf16(a0[m], b[n], acc0[m][n], 0, 0, 0);
        acc1[m][n] = __builtin_amdgcn_mfma_f32_16x16x32_bf16(a1[m], b[n], acc1[m][n], 0, 0, 0);
      }
    __builtin_amdgcn_s_barrier();
    __builtin_amdgcn_sched_barrier(0);        // no gl_lds sinks above barrier
    if (t + 2 < NT) stage(t + 2);
  }

  // ---- epilogue x2: C/D layout col=lane&15, row=(lane>>4)*4+reg  [m89-verified]
  if constexpr (IS_G1) {
#pragma unroll
    for (int m = 0; m < 4; ++m) {
#pragma unroll
      for (int i = 0; i < 4; ++i) {
        int lrow = bx0 * 128 + wr * 64 + m * 16 + g4 * 4 + i;
        if (lrow < Me) {
          size_t grow = (size_t)(off_e + lrow);
#pragma unroll
          for (int n = 0; n < 4; ++n) {
            int col = by * 128 + wc * 64 + n * 16 + r16;
            float v = acc0[m][n][i] + bias[e * NDIM + col];
            Hkb[(size_t)(col >> 5) * A_KT + grow * 32 + (col & 31)] = f2bf(fmaxf(v, 0.f));
          }
        }
      }
    }
    if (has1) {
#pragma unroll
      for (int m = 0; m < 4; ++m) {
#pragma unroll
        for (int i = 0; i < 4; ++i) {
          int lrow = bx1 * 128 + wr * 64 + m * 16 + g4 * 4 + i;
          if (lrow < Me) {
            size_t grow = (size_t)(off_e + lrow);
#pragma unroll
            for (int n = 0; n < 4; ++n) {
              int col = by * 128 + wc * 64 + n * 16 + r16;
              float v = acc1[m][n][i] + bias[e * NDIM + col];
              Hkb[(size_t)(col >> 5) * A_KT + grow * 32 + (col & 31)] = f2bf(fmaxf(v, 0.f));
            }
          }
        }
      }
    }
  } else {
#pragma unroll
    for (int m = 0; m < 4; ++m) {
#pragma unroll
      for (int i = 0; i < 4; ++i) {
        int lrow = bx0 * 128 + wr * 64 + m * 16 + g4 * 4 + i;
        if (lrow < Me) {
          int tok = lists[e * NTOK + lrow];
          float w = wts[e * NTOK + lrow];
          float* orow = Out + (size_t)tok * NDIM + by * 128;
#pragma unroll
          for (int n = 0; n < 4; ++n) {
            int col = wc * 64 + n * 16 + r16;
            float v = acc0[m][n][i] + (kh == 0 ? bias[e * NDIM + by * 128 + col] : 0.f);
            atomicAdd(orow + col, w * v);  // 4 adds/element (2 experts x 2 kh), commutative
          }
        }
      }
    }
    if (has1) {
#pragma unroll
      for (int m = 0; m < 4; ++m) {
#pragma unroll
        for (int i = 0; i < 4; ++i) {
          int lrow = bx1 * 128 + wr * 64 + m * 16 + g4 * 4 + i;
          if (lrow < Me) {
            int tok = lists[e * NTOK + lrow];
            float w = wts[e * NTOK + lrow];
            float* orow = Out + (size_t)tok * NDIM + by * 128;
#pragma unroll
            for (int n = 0; n < 4; ++n) {
              int col = wc * 64 + n * 16 + r16;
              float v = acc1[m][n][i] + (kh == 0 ? bias[e * NDIM + by * 128 + col] : 0.f);
              atomicAdd(orow + col, w * v);
            }
          }
        }
      }
    }
  }
}

extern "C" void kernel_launch(void* const* d_in, const int* in_sizes, int n_in,
                              void* d_out, int out_size, void* d_ws, size_t ws_size,
                              hipStream_t stream) {
  (void)in_sizes; (void)n_in; (void)ws_size;
  const float* x     = (const float*)d_in[0];
  const float* W1    = (const float*)d_in[1];
  const float* b1    = (const float*)d_in[2];
  const float* W2    = (const float*)d_in[3];
  const float* b2    = (const float*)d_in[4];
  const float* Wg    = (const float*)d_in[5];
  const float* bg    = (const float*)d_in[6];
  const float* noise = (const float*)d_in[7];
  float* out = (float*)d_out;

  char* ws = (char*)d_ws;
  int*            counts = (int*)(ws + OFF_CNT);
  int*            tb1    = (int*)(ws + OFF_TB1);
  int*            tb2    = (int*)(ws + OFF_TB2);
  int2*           tki    = (int2*)(ws + OFF_TKI);
  float2*         tkw    = (float2*)(ws + OFF_TKW);
  int*            lists  = (int*)(ws + OFF_LIST);
  float*          wts    = (float*)(ws + OFF_WTS);
  unsigned short* xbf    = (unsigned short*)(ws + OFF_XBF);
  unsigned short* akb    = (unsigned short*)(ws + OFF_AKB);
  unsigned short* w1kb   = (unsigned short*)(ws + OFF_W1KB);
  unsigned short* w2kb   = (unsigned short*)(ws + OFF_W2KB);
  unsigned short* hkb    = (unsigned short*)(ws + OFF_HKB);

  hipMemsetAsync(d_out, 0, (size_t)out_size * sizeof(float), stream);
  hipMemsetAsync(counts, 0, 256, stream);

  gate_kernel<<<NTOK / 4, 256, 0, stream>>>(x, Wg, bg, noise, tki, tkw, xbf);
  scatter_kernel<<<NEXP, 256, 0, stream>>>(tki, tkw, counts, lists, wts);
  build_tiles_kernel<<<1, 256, 0, stream>>>(counts, tb1, tb2);
  gather_a_kernel<<<dim3(GROWS / 256, DDIM / 32), 256, 0, stream>>>(xbf, counts, lists, akb);
  transpose_cvt_kernel<<<dim3(HDIM / 64, DDIM / 64, NEXP), 256, 0, stream>>>(W1, w1kb, DDIM, HDIM);
  transpose_cvt_kernel<<<dim3(DDIM / 64, HDIM / 64, NEXP), 256, 0, stream>>>(W2, w2kb, HDIM, DDIM);

  moe_gemm_kernel<DDIM, HDIM, 1, true>
      <<<MAXT1, 256, 0, stream>>>(akb, w1kb, b1, counts, lists, wts, tb1, hkb, nullptr);
  moe_gemm_kernel<HDIM, DDIM, 2, false>
      <<<MAXT2, 256, 0, stream>>>(hkb, w2kb, b2, counts, lists, wts, tb2, nullptr, out);
}

// Round 21
// 366.194 us; speedup vs baseline: 1.7935x; 1.7935x over previous
//
#include <hip/hip_runtime.h>
#include <stdint.h>
#include <stddef.h>

#define NTOK 8192
#define DDIM 1024
#define HDIM 2048
#define NEXP 8
#define GROWS 16384   // total grouped rows = 2*NTOK (top-2)

typedef __attribute__((ext_vector_type(8))) short short8;
typedef __attribute__((ext_vector_type(8))) unsigned short ushort8;
typedef __attribute__((ext_vector_type(4))) float floatx4;

#define AS1 __attribute__((address_space(1)))
#define AS3 __attribute__((address_space(3)))

// 128-row tiles: max row-tiles summed over experts = floor(16384/128)+8 = 136
#define MAXRT 136
#define MAXT1 (MAXRT * (HDIM / 128))   // 2176
#define MAXT2 (MAXRT * (DDIM / 128))   // 1088

// ws layout (bytes)
constexpr size_t OFF_CNT  = 0;                                         // 8 ints
constexpr size_t OFF_TB1  = 256;                                       // 1+MAXT1 ints
constexpr size_t OFF_TB2  = OFF_TB1 + 8960;                            // 1+MAXT2 ints
constexpr size_t OFF_TKI  = OFF_TB2 + 4608;                            // NTOK int2
constexpr size_t OFF_TKW  = OFF_TKI + (size_t)NTOK * 8;                // NTOK float2
constexpr size_t OFF_LIST = OFF_TKW + (size_t)NTOK * 8;                // E*N ints
constexpr size_t OFF_WTS  = OFF_LIST + (size_t)NEXP * NTOK * 4;        // E*N floats
constexpr size_t OFF_XBF  = OFF_WTS + (size_t)NEXP * NTOK * 4;         // N*D bf16 (row-major)
constexpr size_t OFF_AKB  = OFF_XBF + (size_t)NTOK * DDIM * 2;         // [32][GROWS][32] bf16
constexpr size_t OFF_W1KB = OFF_AKB + (size_t)GROWS * DDIM * 2;        // [e][32][HDIM][32]
constexpr size_t OFF_W2KB = OFF_W1KB + (size_t)NEXP * DDIM * HDIM * 2; // [e][64][DDIM][32]
constexpr size_t OFF_HKB  = OFF_W2KB + (size_t)NEXP * DDIM * HDIM * 2; // [64][GROWS][32]

__device__ __forceinline__ unsigned short f2bf(float f) {
  union { float f; unsigned u; } v; v.f = f;
  unsigned r = v.u + 0x7FFFu + ((v.u >> 16) & 1u);   // RNE, finite inputs
  return (unsigned short)(r >> 16);
}

// ---------------- gating (one wave per token) + fused x->bf16 pack; NO atomics ----------------
__global__ __launch_bounds__(256) void gate_kernel(
    const float* __restrict__ x, const float* __restrict__ Wg,
    const float* __restrict__ bg, const float* __restrict__ noise,
    int2* __restrict__ tki, float2* __restrict__ tkw,
    unsigned short* __restrict__ xbf) {
  int lane = threadIdx.x & 63;
  int wid  = threadIdx.x >> 6;
  int token = blockIdx.x * 4 + wid;
  const float* xr = x + (size_t)token * DDIM;
  unsigned short* xo = xbf + (size_t)token * DDIM;
  double acc[NEXP];
#pragma unroll
  for (int e = 0; e < NEXP; ++e) acc[e] = 0.0;
  for (int d = lane; d < DDIM; d += 64) {
    float xv = xr[d];
    xo[d] = f2bf(xv);
    const floatx4* wp = (const floatx4*)(Wg + d * NEXP);
    floatx4 w0 = wp[0], w1 = wp[1];
#pragma unroll
    for (int j = 0; j < 4; ++j) {
      acc[j]     += (double)xv * (double)w0[j];
      acc[4 + j] += (double)xv * (double)w1[j];
    }
  }
#pragma unroll
  for (int e = 0; e < NEXP; ++e)
#pragma unroll
    for (int off = 32; off > 0; off >>= 1) acc[e] += __shfl_xor(acc[e], off);
  if (lane == 0) {
    float nv[NEXP];
#pragma unroll
    for (int e = 0; e < NEXP; ++e) {
      float lg = (float)(acc[e] + (double)bg[e]);
      nv[e] = lg + 0.1f * noise[token * NEXP + e];
    }
    int i1 = 0; float v1 = nv[0];
#pragma unroll
    for (int e = 1; e < NEXP; ++e) if (nv[e] > v1) { v1 = nv[e]; i1 = e; }
    int i2 = -1; float v2 = -3.4e38f;
#pragma unroll
    for (int e = 0; e < NEXP; ++e) if (e != i1 && nv[e] > v2) { v2 = nv[e]; i2 = e; }
    float tt  = expf(v2 - v1);
    tki[token] = make_int2(i1, i2);
    tkw[token] = make_float2(1.0f / (1.0f + tt), tt / (1.0f + tt));
  }
}

// ---------------- scatter: one block per expert, ballot-compaction, deterministic ----------------
__global__ __launch_bounds__(256) void scatter_kernel(
    const int2* __restrict__ tki, const float2* __restrict__ tkw,
    int* __restrict__ counts, int* __restrict__ lists, float* __restrict__ wts) {
  int e = blockIdx.x;
  int tid = threadIdx.x;
  int lane = tid & 63, wid = tid >> 6;
  __shared__ int wave_cnt[4];
  __shared__ int run_total;
  if (tid == 0) run_total = 0;
  __syncthreads();
  for (int t0 = 0; t0 < NTOK; t0 += 256) {
    int tok = t0 + tid;
    int2 ki = tki[tok];
    float2 kw = tkw[tok];
    bool sel = (ki.x == e) || (ki.y == e);
    float w = (ki.x == e) ? kw.x : kw.y;
    unsigned long long mask = __ballot(sel);
    int pos = __popcll(mask & ((1ull << lane) - 1ull));
    if (lane == 0) wave_cnt[wid] = __popcll(mask);
    __syncthreads();
    int base = run_total;
    for (int i = 0; i < wid; ++i) base += wave_cnt[i];
    if (sel) {
      lists[e * NTOK + base + pos] = tok;
      wts[e * NTOK + base + pos] = w;
    }
    __syncthreads();
    if (tid == 0) run_total += wave_cnt[0] + wave_cnt[1] + wave_cnt[2] + wave_cnt[3];
    __syncthreads();
  }
  if (tid == 0) counts[e] = run_total;
}

// ---------------- gather A into K-blocked grouped panels: akb[kt32][grow][32] ----------------
__global__ __launch_bounds__(256) void gather_a_kernel(
    const unsigned short* __restrict__ xbf, const int* __restrict__ counts,
    const int* __restrict__ lists, unsigned short* __restrict__ akb) {
  int kt   = blockIdx.y;                       // 0..31
  int grow = blockIdx.x * 256 + threadIdx.x;   // 0..16383
  int c[8];
#pragma unroll
  for (int i = 0; i < 8; ++i) c[i] = counts[i];
  int e = 0, off = 0;
#pragma unroll
  for (int i = 0; i < 8; ++i)
    if (e == i && grow >= off + c[i]) { off += c[i]; e = i + 1; }
  int tok = lists[e * NTOK + (grow - off)];
  const ushort8* s = (const ushort8*)(xbf + (size_t)tok * DDIM + kt * 32);
  ushort8* d = (ushort8*)(akb + (size_t)kt * GROWS * 32 + (size_t)grow * 32);
  d[0] = s[0]; d[1] = s[1]; d[2] = s[2]; d[3] = s[3];
}

// ---------------- tile-table build: 128-row tiles, order (e, by, bx-fastest) ----------------
__global__ __launch_bounds__(256) void build_tiles_kernel(
    const int* __restrict__ counts, int* __restrict__ tb1, int* __restrict__ tb2) {
  int tid = threadIdx.x;
  int ct[8], cum[9];
  cum[0] = 0;
#pragma unroll
  for (int e = 0; e < 8; ++e) { ct[e] = (counts[e] + 127) >> 7; cum[e + 1] = cum[e] + ct[e]; }
  int nt = cum[8];
  constexpr int NBY1 = HDIM / 128, NBY2 = DDIM / 128;
  if (tid == 0) { tb1[0] = nt * NBY1; tb2[0] = nt * NBY2; }
  for (int idx = tid; idx < nt * NBY1; idx += 256) {
    int e = 0;
    while (idx >= cum[e + 1] * NBY1) ++e;
    int r = idx - cum[e] * NBY1;
    int by = r / ct[e], bx = r - by * ct[e];
    tb1[1 + idx] = (e << 16) | (bx << 8) | by;
  }
  for (int idx = tid; idx < nt * NBY2; idx += 256) {
    int e = 0;
    while (idx >= cum[e + 1] * NBY2) ++e;
    int r = idx - cum[e] * NBY2;
    int by = r / ct[e], bx = r - by * ct[e];
    tb2[1 + idx] = (e << 16) | (bx << 8) | by;
  }
}

// ---------------- W [e][R=K][C] f32 -> K-blocked WT_kb [e][K/32][C][32] bf16 ----------------
__global__ __launch_bounds__(256) void transpose_cvt_kernel(
    const float* __restrict__ W, unsigned short* __restrict__ WT, int R, int C) {
  __shared__ float tile[64][65];
  int e = blockIdx.z;
  const float* Win = W + (size_t)e * R * C;
  unsigned short* Wout = WT + (size_t)e * R * C;
  int c0 = blockIdx.x * 64, r0 = blockIdx.y * 64;   // r0 = k-origin
  int tx = threadIdx.x & 63, ty = threadIdx.x >> 6;
#pragma unroll
  for (int i = ty; i < 64; i += 4)
    tile[i][tx] = Win[(size_t)(r0 + i) * C + c0 + tx];
  __syncthreads();
  int cc = threadIdx.x >> 2, seg = (threadIdx.x & 3) * 16;
  ushort8 o0, o1;
#pragma unroll
  for (int j = 0; j < 8; ++j) o0[j] = f2bf(tile[seg + j][cc]);
#pragma unroll
  for (int j = 0; j < 8; ++j) o1[j] = f2bf(tile[seg + 8 + j][cc]);
  int koff = r0 + seg;
  unsigned short* outp = Wout + (size_t)(koff >> 5) * C * 32
                              + (size_t)(c0 + cc) * 32 + (koff & 31);
  *(ushort8*)(outp) = o0;
  *(ushort8*)(outp + 8) = o1;
}

// ---------------- grouped GEMM: 128x128, BK=32, 4 waves, 2-buf, counted vmcnt, NO setprio ----
// R19 configuration — best of 20 rounds (GEMMs ~153us each, total 367us). K-blocked
// contiguous staging (4KB/instr), counted-vmcnt 2-deep, rule #18/#21 fences, exact tile
// table, XCD-chunk swizzle. All other levers (tile size, BK, depth, schedule, setprio,
// dual-tile intensity) measured neutral or negative in R8-R20.
template <int KDIM, int NDIM, bool IS_G1>
__global__ __launch_bounds__(256) void moe_gemm_kernel(
    const unsigned short* __restrict__ Akb,      // [KDIM/32][GROWS][32]
    const unsigned short* __restrict__ Bkb,      // [e][KDIM/32][NDIM][32]
    const float* __restrict__ bias,
    const int* __restrict__ counts, const int* __restrict__ lists,
    const float* __restrict__ wts, const int* __restrict__ tbl,
    unsigned short* __restrict__ Hkb,            // [HDIM/32][GROWS][32]
    float* __restrict__ Out) {
  __shared__ __align__(16) char smem[32768];
  constexpr int NT = KDIM / 32;
  constexpr size_t A_KT = (size_t)GROWS * 32;
  constexpr size_t B_KT = (size_t)NDIM * 32;

  int ntiles = tbl[0];
  int bid = blockIdx.x;
  if (bid >= ntiles) return;
  // bijective XCD-chunk swizzle within [0, ntiles)  (m204)
  int q = ntiles >> 3, rr = ntiles & 7;
  int xcd = bid & 7, within = bid >> 3;
  int widx = (xcd < rr ? xcd * (q + 1) : rr * (q + 1) + (xcd - rr) * q) + within;
  int desc = tbl[1 + widx];
  int e  = desc >> 16;
  int bx = (desc >> 8) & 0xff;
  int by = desc & 0xff;

  int Me, off_e = 0;
  {
    int c[8];
#pragma unroll
    for (int i = 0; i < 8; ++i) c[i] = counts[i];
    Me = c[e];
#pragma unroll
    for (int i = 0; i < 8; ++i) if (i < e) off_e += c[i];
  }

  int tid = threadIdx.x;
  int lane = tid & 63, wid = tid >> 6;
  int wr = wid >> 1, wc = wid & 1;       // 2x2 waves, 64x64 output each
  int r16 = lane & 15, g4 = lane >> 4;

  // ---- staging sources: row r0=t>>2, stored slot t&3,
  //      source chunk = (t&3)^((r0>>1)&3); rows consecutive 64B -> 4KB contiguous/instr
  int r0 = tid >> 2;
  int ch = ((tid & 3) ^ ((r0 >> 1) & 3)) * 8;
  const unsigned short *sA0, *sA1, *sB0, *sB1;
  {
    int lr0 = bx * 128 + r0, lr1 = lr0 + 64;
    int g0 = off_e + (lr0 < Me ? lr0 : 0);
    int g1 = off_e + (lr1 < Me ? lr1 : 0);
    sA0 = Akb + (size_t)g0 * 32 + ch;
    sA1 = Akb + (size_t)g1 * 32 + ch;
    const unsigned short* be = Bkb + (size_t)e * KDIM * NDIM;
    sB0 = be + (size_t)(by * 128 + r0) * 32 + ch;
    sB1 = be + (size_t)(by * 128 + 64 + r0) * 32 + ch;
  }

  auto stage = [&](int t) {              // 4 gl_lds per thread; each instr = 4KB contiguous
    int buf = t & 1;
    char* da = smem + buf * 8192 + tid * 16;
    char* db = smem + 16384 + buf * 8192 + tid * 16;
    size_t ao = (size_t)t * A_KT, bo = (size_t)t * B_KT;
    __builtin_amdgcn_global_load_lds((const AS1 void*)(sA0 + ao), (AS3 void*)da, 16, 0, 0);
    __builtin_amdgcn_global_load_lds((const AS1 void*)(sA1 + ao), (AS3 void*)(da + 4096), 16, 0, 0);
    __builtin_amdgcn_global_load_lds((const AS1 void*)(sB0 + bo), (AS3 void*)db, 16, 0, 0);
    __builtin_amdgcn_global_load_lds((const AS1 void*)(sB1 + bo), (AS3 void*)(db + 4096), 16, 0, 0);
  };

  // ---- fragment read offsets (swizzled): row*64 + ((g4 ^ ((row>>1)&3))*16)
  int aoff[4], boff[4];
#pragma unroll
  for (int m = 0; m < 4; ++m) {
    int rowa = wr * 64 + m * 16 + r16;
    aoff[m] = rowa * 64 + ((g4 ^ ((rowa >> 1) & 3)) * 16);
  }
#pragma unroll
  for (int n = 0; n < 4; ++n) {
    int rowb = wc * 64 + n * 16 + r16;
    boff[n] = 16384 + rowb * 64 + ((g4 ^ ((rowb >> 1) & 3)) * 16);
  }

  floatx4 acc[4][4];
#pragma unroll
  for (int m = 0; m < 4; ++m)
#pragma unroll
    for (int n = 0; n < 4; ++n) acc[m][n] = (floatx4){0.f, 0.f, 0.f, 0.f};

  stage(0);
  stage(1);

  for (int t = 0; t < NT; ++t) {
    if (t + 1 < NT) { asm volatile("s_waitcnt vmcnt(4)" ::: "memory"); }
    else            { asm volatile("s_waitcnt vmcnt(0)" ::: "memory"); }
    __builtin_amdgcn_s_barrier();
    __builtin_amdgcn_sched_barrier(0);        // no ds_read hoists above barrier (rule #18)
    const char* pa = smem + (t & 1) * 8192;
    const char* pb = smem + (t & 1) * 8192;   // boff already includes +16384
    short8 a[4], b[4];
#pragma unroll
    for (int m = 0; m < 4; ++m) a[m] = *(const short8*)(pa + aoff[m]);
#pragma unroll
    for (int n = 0; n < 4; ++n) b[n] = *(const short8*)(pb + boff[n]);
#pragma unroll
    for (int m = 0; m < 4; ++m)
#pragma unroll
      for (int n = 0; n < 4; ++n)
        acc[m][n] = __builtin_amdgcn_mfma_f32_16x16x32_bf16(a[m], b[n], acc[m][n], 0, 0, 0);
    __builtin_amdgcn_s_barrier();
    __builtin_amdgcn_sched_barrier(0);        // no gl_lds sinks above barrier
    if (t + 2 < NT) stage(t + 2);
  }

  // ---- epilogue: C/D layout col=lane&15, row=(lane>>4)*4+reg  [m89-verified]
  if constexpr (IS_G1) {
#pragma unroll
    for (int m = 0; m < 4; ++m) {
#pragma unroll
      for (int i = 0; i < 4; ++i) {
        int lrow = bx * 128 + wr * 64 + m * 16 + g4 * 4 + i;
        if (lrow < Me) {
          size_t grow = (size_t)(off_e + lrow);
#pragma unroll
          for (int n = 0; n < 4; ++n) {
            int col = by * 128 + wc * 64 + n * 16 + r16;
            float v = acc[m][n][i] + bias[e * NDIM + col];
            Hkb[(size_t)(col >> 5) * A_KT + grow * 32 + (col & 31)] = f2bf(fmaxf(v, 0.f));
          }
        }
      }
    }
  } else {
#pragma unroll
    for (int m = 0; m < 4; ++m) {
#pragma unroll
      for (int i = 0; i < 4; ++i) {
        int lrow = bx * 128 + wr * 64 + m * 16 + g4 * 4 + i;
        if (lrow < Me) {
          int tok = lists[e * NTOK + lrow];
          float w = wts[e * NTOK + lrow];
          float* orow = Out + (size_t)tok * NDIM + by * 128;
#pragma unroll
          for (int n = 0; n < 4; ++n) {
            int col = wc * 64 + n * 16 + r16;
            float v = acc[m][n][i] + bias[e * NDIM + by * 128 + col];
            atomicAdd(orow + col, w * v);  // exactly 2 adds/element, commutative
          }
        }
      }
    }
  }
}

extern "C" void kernel_launch(void* const* d_in, const int* in_sizes, int n_in,
                              void* d_out, int out_size, void* d_ws, size_t ws_size,
                              hipStream_t stream) {
  (void)in_sizes; (void)n_in; (void)ws_size;
  const float* x     = (const float*)d_in[0];
  const float* W1    = (const float*)d_in[1];
  const float* b1    = (const float*)d_in[2];
  const float* W2    = (const float*)d_in[3];
  const float* b2    = (const float*)d_in[4];
  const float* Wg    = (const float*)d_in[5];
  const float* bg    = (const float*)d_in[6];
  const float* noise = (const float*)d_in[7];
  float* out = (float*)d_out;

  char* ws = (char*)d_ws;
  int*            counts = (int*)(ws + OFF_CNT);
  int*            tb1    = (int*)(ws + OFF_TB1);
  int*            tb2    = (int*)(ws + OFF_TB2);
  int2*           tki    = (int2*)(ws + OFF_TKI);
  float2*         tkw    = (float2*)(ws + OFF_TKW);
  int*            lists  = (int*)(ws + OFF_LIST);
  float*          wts    = (float*)(ws + OFF_WTS);
  unsigned short* xbf    = (unsigned short*)(ws + OFF_XBF);
  unsigned short* akb    = (unsigned short*)(ws + OFF_AKB);
  unsigned short* w1kb   = (unsigned short*)(ws + OFF_W1KB);
  unsigned short* w2kb   = (unsigned short*)(ws + OFF_W2KB);
  unsigned short* hkb    = (unsigned short*)(ws + OFF_HKB);

  hipMemsetAsync(d_out, 0, (size_t)out_size * sizeof(float), stream);
  hipMemsetAsync(counts, 0, 256, stream);

  gate_kernel<<<NTOK / 4, 256, 0, stream>>>(x, Wg, bg, noise, tki, tkw, xbf);
  scatter_kernel<<<NEXP, 256, 0, stream>>>(tki, tkw, counts, lists, wts);
  build_tiles_kernel<<<1, 256, 0, stream>>>(counts, tb1, tb2);
  gather_a_kernel<<<dim3(GROWS / 256, DDIM / 32), 256, 0, stream>>>(xbf, counts, lists, akb);
  transpose_cvt_kernel<<<dim3(HDIM / 64, DDIM / 64, NEXP), 256, 0, stream>>>(W1, w1kb, DDIM, HDIM);
  transpose_cvt_kernel<<<dim3(DDIM / 64, HDIM / 64, NEXP), 256, 0, stream>>>(W2, w2kb, HDIM, DDIM);

  moe_gemm_kernel<DDIM, HDIM, true>
      <<<MAXT1, 256, 0, stream>>>(akb, w1kb, b1, counts, lists, wts, tb1, hkb, nullptr);
  moe_gemm_kernel<HDIM, DDIM, false>
      <<<MAXT2, 256, 0, stream>>>(hkb, w2kb, b2, counts, lists, wts, tb2, nullptr, out);
}

// Round 22
// 341.566 us; speedup vs baseline: 1.9228x; 1.0721x over previous
//
#include <hip/hip_runtime.h>
#include <stdint.h>
#include <stddef.h>

#define NTOK 8192
#define DDIM 1024
#define HDIM 2048
#define NEXP 8
#define GROWS 16384   // total grouped rows = 2*NTOK (top-2)

typedef __attribute__((ext_vector_type(8))) short short8;
typedef __attribute__((ext_vector_type(8))) unsigned short ushort8;
typedef __attribute__((ext_vector_type(4))) float floatx4;

#define AS1 __attribute__((address_space(1)))
#define AS3 __attribute__((address_space(3)))

// 128-row tiles: max row-tiles summed over experts = floor(16384/128)+8 = 136
#define MAXRT 136
#define MAXT1 (MAXRT * (HDIM / 128))   // 2176
#define MAXT2 (MAXRT * (DDIM / 128))   // 1088

// ws layout (bytes)
constexpr size_t OFF_CNT  = 0;                                         // 8 ints
constexpr size_t OFF_TB1  = 256;                                       // 1+MAXT1 ints
constexpr size_t OFF_TB2  = OFF_TB1 + 8960;                            // 1+MAXT2 ints
constexpr size_t OFF_TKI  = OFF_TB2 + 4608;                            // NTOK int2
constexpr size_t OFF_TKW  = OFF_TKI + (size_t)NTOK * 8;                // NTOK float2
constexpr size_t OFF_LIST = OFF_TKW + (size_t)NTOK * 8;                // E*N ints
constexpr size_t OFF_WTS  = OFF_LIST + (size_t)NEXP * NTOK * 4;        // E*N floats
constexpr size_t OFF_XBF  = OFF_WTS + (size_t)NEXP * NTOK * 4;         // N*D bf16 (row-major)
constexpr size_t OFF_AKB  = OFF_XBF + (size_t)NTOK * DDIM * 2;         // [32][GROWS][32] bf16
constexpr size_t OFF_W1KB = OFF_AKB + (size_t)GROWS * DDIM * 2;        // [e][32][HDIM][32]
constexpr size_t OFF_W2KB = OFF_W1KB + (size_t)NEXP * DDIM * HDIM * 2; // [e][64][DDIM][32]
constexpr size_t OFF_HKB  = OFF_W2KB + (size_t)NEXP * DDIM * HDIM * 2; // [64][GROWS][32]

__device__ __forceinline__ unsigned short f2bf(float f) {
  union { float f; unsigned u; } v; v.f = f;
  unsigned r = v.u + 0x7FFFu + ((v.u >> 16) & 1u);   // RNE, finite inputs
  return (unsigned short)(r >> 16);
}

// ---------------- gating (one wave per token) + fused x->bf16 pack; NO atomics ----------------
__global__ __launch_bounds__(256) void gate_kernel(
    const float* __restrict__ x, const float* __restrict__ Wg,
    const float* __restrict__ bg, const float* __restrict__ noise,
    int2* __restrict__ tki, float2* __restrict__ tkw,
    unsigned short* __restrict__ xbf) {
  int lane = threadIdx.x & 63;
  int wid  = threadIdx.x >> 6;
  int token = blockIdx.x * 4 + wid;
  const float* xr = x + (size_t)token * DDIM;
  unsigned short* xo = xbf + (size_t)token * DDIM;
  double acc[NEXP];
#pragma unroll
  for (int e = 0; e < NEXP; ++e) acc[e] = 0.0;
  for (int d = lane; d < DDIM; d += 64) {
    float xv = xr[d];
    xo[d] = f2bf(xv);
    const floatx4* wp = (const floatx4*)(Wg + d * NEXP);
    floatx4 w0 = wp[0], w1 = wp[1];
#pragma unroll
    for (int j = 0; j < 4; ++j) {
      acc[j]     += (double)xv * (double)w0[j];
      acc[4 + j] += (double)xv * (double)w1[j];
    }
  }
#pragma unroll
  for (int e = 0; e < NEXP; ++e)
#pragma unroll
    for (int off = 32; off > 0; off >>= 1) acc[e] += __shfl_xor(acc[e], off);
  if (lane == 0) {
    float nv[NEXP];
#pragma unroll
    for (int e = 0; e < NEXP; ++e) {
      float lg = (float)(acc[e] + (double)bg[e]);
      nv[e] = lg + 0.1f * noise[token * NEXP + e];
    }
    int i1 = 0; float v1 = nv[0];
#pragma unroll
    for (int e = 1; e < NEXP; ++e) if (nv[e] > v1) { v1 = nv[e]; i1 = e; }
    int i2 = -1; float v2 = -3.4e38f;
#pragma unroll
    for (int e = 0; e < NEXP; ++e) if (e != i1 && nv[e] > v2) { v2 = nv[e]; i2 = e; }
    float tt  = expf(v2 - v1);
    tki[token] = make_int2(i1, i2);
    tkw[token] = make_float2(1.0f / (1.0f + tt), tt / (1.0f + tt));
  }
}

// ---------------- scatter: one block per expert, ballot-compaction, deterministic ----------------
__global__ __launch_bounds__(256) void scatter_kernel(
    const int2* __restrict__ tki, const float2* __restrict__ tkw,
    int* __restrict__ counts, int* __restrict__ lists, float* __restrict__ wts) {
  int e = blockIdx.x;
  int tid = threadIdx.x;
  int lane = tid & 63, wid = tid >> 6;
  __shared__ int wave_cnt[4];
  __shared__ int run_total;
  if (tid == 0) run_total = 0;
  __syncthreads();
  for (int t0 = 0; t0 < NTOK; t0 += 256) {
    int tok = t0 + tid;
    int2 ki = tki[tok];
    float2 kw = tkw[tok];
    bool sel = (ki.x == e) || (ki.y == e);
    float w = (ki.x == e) ? kw.x : kw.y;
    unsigned long long mask = __ballot(sel);
    int pos = __popcll(mask & ((1ull << lane) - 1ull));
    if (lane == 0) wave_cnt[wid] = __popcll(mask);
    __syncthreads();
    int base = run_total;
    for (int i = 0; i < wid; ++i) base += wave_cnt[i];
    if (sel) {
      lists[e * NTOK + base + pos] = tok;
      wts[e * NTOK + base + pos] = w;
    }
    __syncthreads();
    if (tid == 0) run_total += wave_cnt[0] + wave_cnt[1] + wave_cnt[2] + wave_cnt[3];
    __syncthreads();
  }
  if (tid == 0) counts[e] = run_total;
}

// ---------------- gather A into K-blocked grouped panels: akb[kt32][grow][32] ----------------
__global__ __launch_bounds__(256) void gather_a_kernel(
    const unsigned short* __restrict__ xbf, const int* __restrict__ counts,
    const int* __restrict__ lists, unsigned short* __restrict__ akb) {
  int kt   = blockIdx.y;                       // 0..31
  int grow = blockIdx.x * 256 + threadIdx.x;   // 0..16383
  int c[8];
#pragma unroll
  for (int i = 0; i < 8; ++i) c[i] = counts[i];
  int e = 0, off = 0;
#pragma unroll
  for (int i = 0; i < 8; ++i)
    if (e == i && grow >= off + c[i]) { off += c[i]; e = i + 1; }
  int tok = lists[e * NTOK + (grow - off)];
  const ushort8* s = (const ushort8*)(xbf + (size_t)tok * DDIM + kt * 32);
  ushort8* d = (ushort8*)(akb + (size_t)kt * GROWS * 32 + (size_t)grow * 32);
  d[0] = s[0]; d[1] = s[1]; d[2] = s[2]; d[3] = s[3];
}

// ---------------- tile-table build: 128-row tiles, order (e, by, bx-fastest) ----------------
__global__ __launch_bounds__(256) void build_tiles_kernel(
    const int* __restrict__ counts, int* __restrict__ tb1, int* __restrict__ tb2) {
  int tid = threadIdx.x;
  int ct[8], cum[9];
  cum[0] = 0;
#pragma unroll
  for (int e = 0; e < 8; ++e) { ct[e] = (counts[e] + 127) >> 7; cum[e + 1] = cum[e] + ct[e]; }
  int nt = cum[8];
  constexpr int NBY1 = HDIM / 128, NBY2 = DDIM / 128;
  if (tid == 0) { tb1[0] = nt * NBY1; tb2[0] = nt * NBY2; }
  for (int idx = tid; idx < nt * NBY1; idx += 256) {
    int e = 0;
    while (idx >= cum[e + 1] * NBY1) ++e;
    int r = idx - cum[e] * NBY1;
    int by = r / ct[e], bx = r - by * ct[e];
    tb1[1 + idx] = (e << 16) | (bx << 8) | by;
  }
  for (int idx = tid; idx < nt * NBY2; idx += 256) {
    int e = 0;
    while (idx >= cum[e + 1] * NBY2) ++e;
    int r = idx - cum[e] * NBY2;
    int by = r / ct[e], bx = r - by * ct[e];
    tb2[1 + idx] = (e << 16) | (bx << 8) | by;
  }
}

// ---------------- W [e][R=K][C] f32 -> K-blocked WT_kb [e][K/32][C][32] bf16 ----------------
__global__ __launch_bounds__(256) void transpose_cvt_kernel(
    const float* __restrict__ W, unsigned short* __restrict__ WT, int R, int C) {
  __shared__ float tile[64][65];
  int e = blockIdx.z;
  const float* Win = W + (size_t)e * R * C;
  unsigned short* Wout = WT + (size_t)e * R * C;
  int c0 = blockIdx.x * 64, r0 = blockIdx.y * 64;   // r0 = k-origin
  int tx = threadIdx.x & 63, ty = threadIdx.x >> 6;
#pragma unroll
  for (int i = ty; i < 64; i += 4)
    tile[i][tx] = Win[(size_t)(r0 + i) * C + c0 + tx];
  __syncthreads();
  int cc = threadIdx.x >> 2, seg = (threadIdx.x & 3) * 16;
  ushort8 o0, o1;
#pragma unroll
  for (int j = 0; j < 8; ++j) o0[j] = f2bf(tile[seg + j][cc]);
#pragma unroll
  for (int j = 0; j < 8; ++j) o1[j] = f2bf(tile[seg + 8 + j][cc]);
  int koff = r0 + seg;
  unsigned short* outp = Wout + (size_t)(koff >> 5) * C * 32
                              + (size_t)(c0 + cc) * 32 + (koff & 31);
  *(ushort8*)(outp) = o0;
  *(ushort8*)(outp + 8) = o1;
}

// ---------------- grouped GEMM: 128x128, BK=32, 8 waves (2Mx4N), <=128 regs/wave ----------
// R21 synthesis: occupancy quantizes on unified VGPR+AGPR at 64/128/256 (m69). All prior
// rounds sat at 132-288 regs -> 8 (or 4) waves/CU; this config targets <=128 total:
// per-wave 64x32 output -> acc[4][2] = 32 AGPR; frags a[4]+b[2] = 48 VGPR; est ~105 total
// -> 16 waves/CU (2 blocks x 8 waves) = DOUBLE the latency-hiding at identical geometry.
// __launch_bounds__(512,4) pins the 128-reg cap (content fits; not R3's (512,6) trap).
// Staging/swizzle/vmcnt/fences = R19 invariants; 2 gl_lds/thread (16B), vmcnt(2)/(0).
template <int KDIM, int NDIM, bool IS_G1>
__global__ __launch_bounds__(512, 4) void moe_gemm_kernel(
    const unsigned short* __restrict__ Akb,      // [KDIM/32][GROWS][32]
    const unsigned short* __restrict__ Bkb,      // [e][KDIM/32][NDIM][32]
    const float* __restrict__ bias,
    const int* __restrict__ counts, const int* __restrict__ lists,
    const float* __restrict__ wts, const int* __restrict__ tbl,
    unsigned short* __restrict__ Hkb,            // [HDIM/32][GROWS][32]
    float* __restrict__ Out) {
  __shared__ __align__(16) char smem[32768];
  constexpr int NT = KDIM / 32;
  constexpr size_t A_KT = (size_t)GROWS * 32;
  constexpr size_t B_KT = (size_t)NDIM * 32;

  int ntiles = tbl[0];
  int bid = blockIdx.x;
  if (bid >= ntiles) return;
  // bijective XCD-chunk swizzle within [0, ntiles)  (m204)
  int q = ntiles >> 3, rr = ntiles & 7;
  int xcd = bid & 7, within = bid >> 3;
  int widx = (xcd < rr ? xcd * (q + 1) : rr * (q + 1) + (xcd - rr) * q) + within;
  int desc = tbl[1 + widx];
  int e  = desc >> 16;
  int bx = (desc >> 8) & 0xff;
  int by = desc & 0xff;

  int Me, off_e = 0;
  {
    int c[8];
#pragma unroll
    for (int i = 0; i < 8; ++i) c[i] = counts[i];
    Me = c[e];
#pragma unroll
    for (int i = 0; i < 8; ++i) if (i < e) off_e += c[i];
  }

  int tid = threadIdx.x;
  int lane = tid & 63, wid = tid >> 6;
  int wr = wid >> 2, wc = wid & 3;       // 2(M) x 4(N) waves; per-wave out 64x32
  int r16 = lane & 15, g4 = lane >> 4;

  // ---- staging sources: thread t -> row r0 = tid>>2 (0..127), stored slot tid&3,
  //      source chunk = (tid&3)^((r0>>1)&3); rows consecutive 64B -> coalesced 1KB/wave
  int r0 = tid >> 2;
  int ch = ((tid & 3) ^ ((r0 >> 1) & 3)) * 8;
  const unsigned short *sA, *sB;
  {
    int lr = bx * 128 + r0;
    int g = off_e + (lr < Me ? lr : 0);
    sA = Akb + (size_t)g * 32 + ch;
    sB = Bkb + (size_t)e * KDIM * NDIM + (size_t)(by * 128 + r0) * 32 + ch;
  }

  auto stage = [&](int t) {              // 2 gl_lds per thread (A:1, B:1)
    int buf = t & 1;
    char* da = smem + buf * 8192 + tid * 16;
    char* db = smem + 16384 + buf * 8192 + tid * 16;
    __builtin_amdgcn_global_load_lds((const AS1 void*)(sA + (size_t)t * A_KT), (AS3 void*)da, 16, 0, 0);
    __builtin_amdgcn_global_load_lds((const AS1 void*)(sB + (size_t)t * B_KT), (AS3 void*)db, 16, 0, 0);
  };

  // ---- fragment read offsets (swizzled): row*64 + ((g4 ^ ((row>>1)&3))*16)
  int aoff[4], boff[2];
#pragma unroll
  for (int m = 0; m < 4; ++m) {
    int rowa = wr * 64 + m * 16 + r16;
    aoff[m] = rowa * 64 + ((g4 ^ ((rowa >> 1) & 3)) * 16);
  }
#pragma unroll
  for (int n = 0; n < 2; ++n) {
    int rowb = wc * 32 + n * 16 + r16;
    boff[n] = 16384 + rowb * 64 + ((g4 ^ ((rowb >> 1) & 3)) * 16);
  }

  floatx4 acc[4][2];
#pragma unroll
  for (int m = 0; m < 4; ++m)
#pragma unroll
    for (int n = 0; n < 2; ++n) acc[m][n] = (floatx4){0.f, 0.f, 0.f, 0.f};

  stage(0);
  stage(1);

  for (int t = 0; t < NT; ++t) {
    if (t + 1 < NT) { asm volatile("s_waitcnt vmcnt(2)" ::: "memory"); }  // tile t landed; t+1 flying
    else            { asm volatile("s_waitcnt vmcnt(0)" ::: "memory"); }
    __builtin_amdgcn_s_barrier();
    __builtin_amdgcn_sched_barrier(0);        // no ds_read hoists above barrier (rule #18)
    const char* pa = smem + (t & 1) * 8192;
    const char* pb = smem + (t & 1) * 8192;   // boff already includes +16384
    short8 a[4], b[2];
#pragma unroll
    for (int m = 0; m < 4; ++m) a[m] = *(const short8*)(pa + aoff[m]);
#pragma unroll
    for (int n = 0; n < 2; ++n) b[n] = *(const short8*)(pb + boff[n]);
#pragma unroll
    for (int m = 0; m < 4; ++m)
#pragma unroll
      for (int n = 0; n < 2; ++n)
        acc[m][n] = __builtin_amdgcn_mfma_f32_16x16x32_bf16(a[m], b[n], acc[m][n], 0, 0, 0);
    __builtin_amdgcn_s_barrier();
    __builtin_amdgcn_sched_barrier(0);        // no gl_lds sinks above barrier
    if (t + 2 < NT) stage(t + 2);
  }

  // ---- epilogue: C/D layout col=lane&15, row=(lane>>4)*4+reg  [m89-verified]
  if constexpr (IS_G1) {
#pragma unroll
    for (int m = 0; m < 4; ++m) {
#pragma unroll
      for (int i = 0; i < 4; ++i) {
        int lrow = bx * 128 + wr * 64 + m * 16 + g4 * 4 + i;
        if (lrow < Me) {
          size_t grow = (size_t)(off_e + lrow);
#pragma unroll
          for (int n = 0; n < 2; ++n) {
            int col = by * 128 + wc * 32 + n * 16 + r16;
            float v = acc[m][n][i] + bias[e * NDIM + col];
            Hkb[(size_t)(col >> 5) * A_KT + grow * 32 + (col & 31)] = f2bf(fmaxf(v, 0.f));
          }
        }
      }
    }
  } else {
#pragma unroll
    for (int m = 0; m < 4; ++m) {
#pragma unroll
      for (int i = 0; i < 4; ++i) {
        int lrow = bx * 128 + wr * 64 + m * 16 + g4 * 4 + i;
        if (lrow < Me) {
          int tok = lists[e * NTOK + lrow];
          float w = wts[e * NTOK + lrow];
          float* orow = Out + (size_t)tok * NDIM + by * 128;
#pragma unroll
          for (int n = 0; n < 2; ++n) {
            int col = wc * 32 + n * 16 + r16;
            float v = acc[m][n][i] + bias[e * NDIM + by * 128 + col];
            atomicAdd(orow + col, w * v);  // exactly 2 adds/element, commutative
          }
        }
      }
    }
  }
}

extern "C" void kernel_launch(void* const* d_in, const int* in_sizes, int n_in,
                              void* d_out, int out_size, void* d_ws, size_t ws_size,
                              hipStream_t stream) {
  (void)in_sizes; (void)n_in; (void)ws_size;
  const float* x     = (const float*)d_in[0];
  const float* W1    = (const float*)d_in[1];
  const float* b1    = (const float*)d_in[2];
  const float* W2    = (const float*)d_in[3];
  const float* b2    = (const float*)d_in[4];
  const float* Wg    = (const float*)d_in[5];
  const float* bg    = (const float*)d_in[6];
  const float* noise = (const float*)d_in[7];
  float* out = (float*)d_out;

  char* ws = (char*)d_ws;
  int*            counts = (int*)(ws + OFF_CNT);
  int*            tb1    = (int*)(ws + OFF_TB1);
  int*            tb2    = (int*)(ws + OFF_TB2);
  int2*           tki    = (int2*)(ws + OFF_TKI);
  float2*         tkw    = (float2*)(ws + OFF_TKW);
  int*            lists  = (int*)(ws + OFF_LIST);
  float*          wts    = (float*)(ws + OFF_WTS);
  unsigned short* xbf    = (unsigned short*)(ws + OFF_XBF);
  unsigned short* akb    = (unsigned short*)(ws + OFF_AKB);
  unsigned short* w1kb   = (unsigned short*)(ws + OFF_W1KB);
  unsigned short* w2kb   = (unsigned short*)(ws + OFF_W2KB);
  unsigned short* hkb    = (unsigned short*)(ws + OFF_HKB);

  hipMemsetAsync(d_out, 0, (size_t)out_size * sizeof(float), stream);
  hipMemsetAsync(counts, 0, 256, stream);

  gate_kernel<<<NTOK / 4, 256, 0, stream>>>(x, Wg, bg, noise, tki, tkw, xbf);
  scatter_kernel<<<NEXP, 256, 0, stream>>>(tki, tkw, counts, lists, wts);
  build_tiles_kernel<<<1, 256, 0, stream>>>(counts, tb1, tb2);
  gather_a_kernel<<<dim3(GROWS / 256, DDIM / 32), 256, 0, stream>>>(xbf, counts, lists, akb);
  transpose_cvt_kernel<<<dim3(HDIM / 64, DDIM / 64, NEXP), 256, 0, stream>>>(W1, w1kb, DDIM, HDIM);
  transpose_cvt_kernel<<<dim3(DDIM / 64, HDIM / 64, NEXP), 256, 0, stream>>>(W2, w2kb, HDIM, DDIM);

  moe_gemm_kernel<DDIM, HDIM, true>
      <<<MAXT1, 512, 0, stream>>>(akb, w1kb, b1, counts, lists, wts, tb1, hkb, nullptr);
  moe_gemm_kernel<HDIM, DDIM, false>
      <<<MAXT2, 512, 0, stream>>>(hkb, w2kb, b2, counts, lists, wts, tb2, nullptr, out);
}